// Round 3
// baseline (1076.868 us; speedup 1.0000x reference)
//
#include <hip/hip_runtime.h>
#include <stdint.h>

typedef __attribute__((ext_vector_type(4))) float f32x4;
typedef __attribute__((ext_vector_type(8))) short s16x8;
typedef __attribute__((ext_vector_type(4))) short s16x4;
typedef __attribute__((ext_vector_type(4))) int i32x4;

__device__ __forceinline__ unsigned short f2bf(float f) {
  unsigned int u = __builtin_bit_cast(unsigned int, f);
  u += 0x7fffu + ((u >> 16) & 1u);   // RNE round to bf16
  return (unsigned short)(u >> 16);
}

// ---------------------------------------------------------------------------
// Projection GEMM (unchanged from passing round 2): C = P * Q^T + bias, bf16.
// MODE 0: out[m*256+n], bias[n].  MODE 1: vT layout, bias[m].
// ---------------------------------------------------------------------------
template <int MODE>
__global__ __launch_bounds__(512) void proj_kernel(
    const float* __restrict__ P, const float* __restrict__ Q,
    const float* __restrict__ bias, unsigned short* __restrict__ out) {
  __shared__ __align__(16) char lds[32768];
  char* Pl = lds;
  char* Ql = lds + 16384;

  const int tid = threadIdx.x;
  const int m0 = blockIdx.x * 128, n0 = blockIdx.y * 128;
  const int lane = tid & 63, w = tid >> 6;
  const int lr = lane & 15, lg = lane >> 4;
  const int wm = w >> 2, wn = w & 3;

  f32x4 acc[4][2];
#pragma unroll
  for (int a = 0; a < 4; a++)
#pragma unroll
    for (int b2 = 0; b2 < 2; b2++) acc[a][b2] = (f32x4){0.f, 0.f, 0.f, 0.f};

  for (int k0 = 0; k0 < 256; k0 += 64) {
    __syncthreads();
#pragma unroll
    for (int j = 0; j < 2; j++) {
      int c = tid + j * 512;
      int row = c >> 3, cc = c & 7;
      int dst = row * 128 + ((cc * 16) ^ ((row & 7) << 4));
      {
        const float* src = P + (size_t)(m0 + row) * 256 + k0 + cc * 8;
        f32x4 x = *(const f32x4*)src;
        f32x4 y = *(const f32x4*)(src + 4);
        s16x8 pk;
        pk[0] = (short)f2bf(x[0]); pk[1] = (short)f2bf(x[1]);
        pk[2] = (short)f2bf(x[2]); pk[3] = (short)f2bf(x[3]);
        pk[4] = (short)f2bf(y[0]); pk[5] = (short)f2bf(y[1]);
        pk[6] = (short)f2bf(y[2]); pk[7] = (short)f2bf(y[3]);
        *(s16x8*)(Pl + dst) = pk;
      }
      {
        const float* src = Q + (size_t)(n0 + row) * 256 + k0 + cc * 8;
        f32x4 x = *(const f32x4*)src;
        f32x4 y = *(const f32x4*)(src + 4);
        s16x8 pk;
        pk[0] = (short)f2bf(x[0]); pk[1] = (short)f2bf(x[1]);
        pk[2] = (short)f2bf(x[2]); pk[3] = (short)f2bf(x[3]);
        pk[4] = (short)f2bf(y[0]); pk[5] = (short)f2bf(y[1]);
        pk[6] = (short)f2bf(y[2]); pk[7] = (short)f2bf(y[3]);
        *(s16x8*)(Ql + dst) = pk;
      }
    }
    __syncthreads();
#pragma unroll
    for (int ks = 0; ks < 2; ks++) {
      s16x8 af[4], bf[2];
      int kbyte = ks * 64 + lg * 16;
#pragma unroll
      for (int fm = 0; fm < 4; fm++) {
        int row = wm * 64 + fm * 16 + lr;
        af[fm] = *(const s16x8*)(Pl + row * 128 + (kbyte ^ ((row & 7) << 4)));
      }
#pragma unroll
      for (int fn = 0; fn < 2; fn++) {
        int row = wn * 32 + fn * 16 + lr;
        bf[fn] = *(const s16x8*)(Ql + row * 128 + (kbyte ^ ((row & 7) << 4)));
      }
#pragma unroll
      for (int fm = 0; fm < 4; fm++)
#pragma unroll
        for (int fn = 0; fn < 2; fn++)
          acc[fm][fn] = __builtin_amdgcn_mfma_f32_16x16x32_bf16(
              af[fm], bf[fn], acc[fm][fn], 0, 0, 0);
    }
  }

  if (MODE == 0) {
    float bv[2];
#pragma unroll
    for (int fn = 0; fn < 2; fn++) bv[fn] = bias[n0 + wn * 32 + fn * 16 + lr];
#pragma unroll
    for (int fm = 0; fm < 4; fm++)
#pragma unroll
      for (int i = 0; i < 4; i++) {
        int m = m0 + wm * 64 + fm * 16 + lg * 4 + i;
#pragma unroll
        for (int fn = 0; fn < 2; fn++) {
          int n = n0 + wn * 32 + fn * 16 + lr;
          out[(size_t)m * 256 + n] = f2bf(acc[fm][fn][i] + bv[fn]);
        }
      }
  } else {
#pragma unroll
    for (int fm = 0; fm < 4; fm++)
#pragma unroll
      for (int i = 0; i < 4; i++) {
        int m = m0 + wm * 64 + fm * 16 + lg * 4 + i;  // d index
        float bm = bias[m];
#pragma unroll
        for (int fn = 0; fn < 2; fn++) {
          int n = n0 + wn * 32 + fn * 16 + lr;  // global key row
          int bb = n >> 11, nn = n & 2047;
          out[(size_t)bb * 524288 + (size_t)m * 2048 + nn] =
              f2bf(acc[fm][fn][i] + bm);
        }
      }
  }
}

// ---------------------------------------------------------------------------
// Attention. grid 512 = B(32) x q-tiles(16), 512 thr / 8 waves, 64 q-rows.
// Per 64-key tile, 5 phases: stage K/vT -> QK^T MFMA -> sacc->Sf(LDS,f32) ->
// cooperative vectorized epilogue (bias f32x4 NT-load [prefetched], exp, mask,
// weights f32x4 NT-store, bf16->Sl, scalar rowsum) -> PV MFMA.
// LDS 64KB: Kl[0,32K)+Vl[32K,64K); Sf[0,16K)+Sl[16K,24K) alias dead Kl.
// ---------------------------------------------------------------------------
__global__ __launch_bounds__(512, 4) void attn_kernel(
    const unsigned short* __restrict__ qb, const unsigned short* __restrict__ kb,
    const unsigned short* __restrict__ vT, const int* __restrict__ qmask,
    const int* __restrict__ kmask, const float* __restrict__ bias,
    float* __restrict__ out, float* __restrict__ weights,
    float* __restrict__ rowrecip_ws) {
  __shared__ __align__(16) char lds[65536];
  char* Kl = lds;            // [64][512B] swizzled bf16 K-tile
  char* Vl = lds + 32768;    // [256][128B] swizzled bf16 vT-tile
  char* Sf = lds;            // [64][256B] f32 scores, bank-rotated (alias Kl)
  char* Sl = lds + 16384;    // [64][128B] bf16 scores, swizzled (alias Kl)
  float* rowsum_lds = (float*)lds;  // [64] reciprocals, after k-loop only

  int bid = blockIdx.x;
  int swz = (bid & 7) * 64 + (bid >> 3);  // XCD swizzle (512 % 8 == 0)
  int b = swz >> 4, qt = swz & 15;
  int q0 = qt * 64;
  const int tid = threadIdx.x, lane = tid & 63, w = tid >> 6;
  const int lr = lane & 15, lg = lane >> 4;
  const int wm = w >> 2, wn = w & 3;

  // phase-B (epilogue) mapping: row pr = tid/8, chunks pc and pc+8 (4 cols ea)
  const int pr = tid >> 3, pc = tid & 7;
  const int qrow_pb = b * 1024 + q0 + pr;
  const int qm_pb = qmask[qrow_pb];
  const float* bias_row = bias + (size_t)qrow_pb * 2048;
  float* wrow = weights + (size_t)qrow_pb * 2048;
  const int* kmask_b = kmask + b * 2048;
  const int prot = ((pr >> 2) & 3) * 64;  // Sf bank rotation for this row

  // Hoisted Q fragments (64 VGPRs)
  s16x8 qf[2][8];
  {
    const unsigned short* qbase =
        qb + (size_t)(b * 1024 + q0 + wm * 32 + lr) * 256 + lg * 8;
#pragma unroll
    for (int fm = 0; fm < 2; fm++)
#pragma unroll
      for (int ks = 0; ks < 8; ks++)
        qf[fm][ks] = *(const s16x8*)(qbase + fm * 16 * 256 + ks * 32);
  }

  f32x4 acc_o[2][4];
#pragma unroll
  for (int a = 0; a < 2; a++)
#pragma unroll
    for (int c = 0; c < 4; c++) acc_o[a][c] = (f32x4){0.f, 0.f, 0.f, 0.f};
  float rs = 0.f;

  const size_t kb_base = (size_t)b * 2048 * 256;
  const size_t vT_base = (size_t)b * 256 * 2048;

  // bias prefetch (tile 0)
  f32x4 bcur0 = __builtin_nontemporal_load((const f32x4*)(bias_row + pc * 4));
  f32x4 bcur1 = __builtin_nontemporal_load((const f32x4*)(bias_row + (pc + 8) * 4));

  for (int kt = 0; kt < 32; kt++) {
    __syncthreads();  // PV + epilogue of kt-1 fully done
    // ---- stage K tile and vT tile (swizzled) ----
#pragma unroll
    for (int j = 0; j < 4; j++) {
      int c = tid + j * 512;
      {
        int row = c >> 5, cb = (c & 31) * 16;
        s16x8 kv = *(const s16x8*)(kb + kb_base +
                                   (size_t)(kt * 64 + row) * 256 + (cb >> 1));
        *(s16x8*)(Kl + row * 512 + (cb ^ ((row & 7) << 4))) = kv;
      }
      {
        int row = c >> 3, cb = (c & 7) * 16;
        s16x8 vv = *(const s16x8*)(vT + vT_base + (size_t)row * 2048 +
                                   kt * 64 + (cb >> 1));
        *(s16x8*)(Vl + row * 128 + (cb ^ ((row & 7) << 4))) = vv;
      }
    }
    __syncthreads();
    // ---- QK^T: wave's 16 key-cols ----
    f32x4 sacc[2];
    sacc[0] = (f32x4){0.f, 0.f, 0.f, 0.f};
    sacc[1] = (f32x4){0.f, 0.f, 0.f, 0.f};
    {
      int krow = wn * 16 + lr;
      int swzk = (krow & 7) << 4;
#pragma unroll
      for (int ks = 0; ks < 8; ks++) {
        s16x8 bfr = *(const s16x8*)(Kl + krow * 512 + ((ks * 64 + lg * 16) ^ swzk));
        sacc[0] = __builtin_amdgcn_mfma_f32_16x16x32_bf16(qf[0][ks], bfr, sacc[0], 0, 0, 0);
        sacc[1] = __builtin_amdgcn_mfma_f32_16x16x32_bf16(qf[1][ks], bfr, sacc[1], 0, 0, 0);
      }
    }
    __syncthreads();  // Kl dead -> Sf/Sl may be written
    // ---- sacc -> Sf (f32, bank-rotated rows) ----
    {
      int col4 = (wn * 16 + lr) * 4;
#pragma unroll
      for (int fm = 0; fm < 2; fm++)
#pragma unroll
        for (int i = 0; i < 4; i++) {
          int row = wm * 32 + fm * 16 + lg * 4 + i;
          *(float*)(Sf + row * 256 + ((col4 + ((row >> 2) & 3) * 64) & 255)) =
              sacc[fm][i];
        }
    }
    __syncthreads();
    // ---- phase B: vectorized epilogue ----
    {
      int ktn = (kt + 1) & 31;  // prefetch next tile's bias (kt=31: unused)
      f32x4 bn0 = __builtin_nontemporal_load(
          (const f32x4*)(bias_row + ktn * 64 + pc * 4));
      f32x4 bn1 = __builtin_nontemporal_load(
          (const f32x4*)(bias_row + ktn * 64 + (pc + 8) * 4));
#pragma unroll
      for (int half = 0; half < 2; half++) {
        int c = pc + half * 8;
        f32x4 bv = half ? bcur1 : bcur0;
        f32x4 sv = *(const f32x4*)(Sf + pr * 256 + ((c * 16 + prot) & 255));
        i32x4 kmv = *(const i32x4*)(kmask_b + kt * 64 + c * 4);
        f32x4 sval;
#pragma unroll
        for (int j = 0; j < 4; j++) {
          float lgt = sv[j] * 0.0625f + bv[j];
          float e = kmv[j] ? __expf(lgt) : 0.0f;
          sval[j] = qm_pb ? e : 1.0f;
        }
        rs += sval[0] + sval[1] + sval[2] + sval[3];
        __builtin_nontemporal_store(sval, (f32x4*)(wrow + kt * 64 + c * 4));
        s16x4 h;
        h[0] = (short)f2bf(sval[0]);
        h[1] = (short)f2bf(sval[1]);
        h[2] = (short)f2bf(sval[2]);
        h[3] = (short)f2bf(sval[3]);
        int cb = c * 8;
        int sb = pr * 128 + ((cb & ~15) ^ ((pr & 7) << 4)) + (cb & 15);
        *(s16x4*)(Sl + sb) = h;
      }
      bcur0 = bn0;
      bcur1 = bn1;
    }
    __syncthreads();  // Sl complete before PV reads it
    // ---- PV: O += S * V ----
#pragma unroll
    for (int ks = 0; ks < 2; ks++) {
      int kbyte = ks * 64 + lg * 16;
      s16x8 af[2], bfr[4];
#pragma unroll
      for (int fm = 0; fm < 2; fm++) {
        int row = wm * 32 + fm * 16 + lr;
        af[fm] = *(const s16x8*)(Sl + row * 128 + (kbyte ^ ((row & 7) << 4)));
      }
#pragma unroll
      for (int fn = 0; fn < 4; fn++) {
        int row = wn * 64 + fn * 16 + lr;
        bfr[fn] = *(const s16x8*)(Vl + row * 128 + (kbyte ^ ((row & 7) << 4)));
      }
#pragma unroll
      for (int fm = 0; fm < 2; fm++)
#pragma unroll
        for (int fn = 0; fn < 4; fn++)
          acc_o[fm][fn] = __builtin_amdgcn_mfma_f32_16x16x32_bf16(
              af[fm], bfr[fn], acc_o[fm][fn], 0, 0, 0);
    }
  }
  // ---- rowsum: 8-lane group reduce, store reciprocal ----
  {
    float tot = rs;
    tot += __shfl_xor(tot, 1);
    tot += __shfl_xor(tot, 2);
    tot += __shfl_xor(tot, 4);
    float rinv = 1.0f / tot;
    if ((tid & 7) == 0) {
      rowsum_lds[pr] = rinv;                       // disjoint from Sl/Vl reads
      rowrecip_ws[b * 1024 + q0 + pr] = rinv;
    }
  }
  __syncthreads();
  // ---- normalized O store ----
#pragma unroll
  for (int fm = 0; fm < 2; fm++)
#pragma unroll
    for (int i = 0; i < 4; i++) {
      int srow = wm * 32 + fm * 16 + lg * 4 + i;
      float rinv = rowsum_lds[srow];
      int qrow = q0 + srow;
#pragma unroll
      for (int fn = 0; fn < 4; fn++) {
        int d = wn * 64 + fn * 16 + lr;
        out[((size_t)b * 1024 + qrow) * 256 + d] = acc_o[fm][fn][i] * rinv;
      }
    }
}

// ---------------------------------------------------------------------------
// Rescale: weights[b,q,:] *= rinv[b,q]  (reciprocal precomputed; NT streams)
// ---------------------------------------------------------------------------
__global__ __launch_bounds__(256) void rescale_kernel(
    float* __restrict__ weights, const float* __restrict__ rinvarr) {
  const size_t total = (size_t)32 * 1024 * 2048 / 4;  // float4 count
  size_t stride = (size_t)gridDim.x * blockDim.x;
  for (size_t i = (size_t)blockIdx.x * blockDim.x + threadIdx.x; i < total;
       i += stride) {
    size_t row = i >> 9;  // 512 float4 per 2048-row
    float rinv = rinvarr[row];
    f32x4 v = __builtin_nontemporal_load((const f32x4*)weights + i);
    v[0] *= rinv; v[1] *= rinv; v[2] *= rinv; v[3] *= rinv;
    __builtin_nontemporal_store(v, (f32x4*)weights + i);
  }
}

extern "C" void kernel_launch(void* const* d_in, const int* in_sizes, int n_in,
                              void* d_out, int out_size, void* d_ws,
                              size_t ws_size, hipStream_t stream) {
  const float* query = (const float*)d_in[0];
  const float* key = (const float*)d_in[1];
  const float* value = (const float*)d_in[2];
  const int* qmask = (const int*)d_in[3];
  const int* kmask = (const int*)d_in[4];
  const float* bias = (const float*)d_in[5];
  const float* Wq = (const float*)d_in[6];
  const float* bq = (const float*)d_in[7];
  const float* Wk = (const float*)d_in[8];
  const float* bk = (const float*)d_in[9];
  const float* Wv = (const float*)d_in[10];
  const float* bv = (const float*)d_in[11];

  float* out = (float*)d_out;
  float* weights = out + (size_t)32 * 1024 * 256;

  char* ws = (char*)d_ws;
  unsigned short* qb = (unsigned short*)ws;                // 16 MB
  unsigned short* kbb = (unsigned short*)(ws + 16777216);  // 32 MB
  unsigned short* vT = (unsigned short*)(ws + 50331648);   // 32 MB
  float* rowrecip = (float*)(ws + 83886080);               // 128 KB

  proj_kernel<0><<<dim3(256, 2), 512, 0, stream>>>(query, Wq, bq, qb);
  proj_kernel<0><<<dim3(512, 2), 512, 0, stream>>>(key, Wk, bk, kbb);
  proj_kernel<1><<<dim3(2, 512), 512, 0, stream>>>(Wv, value, bv, vT);
  attn_kernel<<<dim3(512), 512, 0, stream>>>(qb, kbb, vT, qmask, kmask, bias,
                                             out, weights, rowrecip);
  rescale_kernel<<<dim3(2048), 256, 0, stream>>>(weights, rowrecip);
}

// Round 5
// 882.236 us; speedup vs baseline: 1.2206x; 1.2206x over previous
//
#include <hip/hip_runtime.h>
#include <stdint.h>

typedef __attribute__((ext_vector_type(4))) float f32x4;
typedef __attribute__((ext_vector_type(8))) short s16x8;
typedef __attribute__((ext_vector_type(4))) short s16x4;
typedef __attribute__((ext_vector_type(4))) int i32x4;

__device__ __forceinline__ unsigned short f2bf(float f) {
  unsigned int u = __builtin_bit_cast(unsigned int, f);
  u += 0x7fffu + ((u >> 16) & 1u);   // RNE round to bf16
  return (unsigned short)(u >> 16);
}

// ---------------------------------------------------------------------------
// Projection GEMM: C = P * Q^T + bias, bf16 out.
// MODE 0: out[m*256+n], bias[n].  MODE 1: vT layout, bias[m].
// ---------------------------------------------------------------------------
template <int MODE>
__global__ __launch_bounds__(512) void proj_kernel(
    const float* __restrict__ P, const float* __restrict__ Q,
    const float* __restrict__ bias, unsigned short* __restrict__ out) {
  __shared__ __align__(16) char lds[32768];
  char* Pl = lds;
  char* Ql = lds + 16384;

  const int tid = threadIdx.x;
  const int m0 = blockIdx.x * 128, n0 = blockIdx.y * 128;
  const int lane = tid & 63, w = tid >> 6;
  const int lr = lane & 15, lg = lane >> 4;
  const int wm = w >> 2, wn = w & 3;

  f32x4 acc[4][2];
#pragma unroll
  for (int a = 0; a < 4; a++)
#pragma unroll
    for (int b2 = 0; b2 < 2; b2++) acc[a][b2] = (f32x4){0.f, 0.f, 0.f, 0.f};

  for (int k0 = 0; k0 < 256; k0 += 64) {
    __syncthreads();
#pragma unroll
    for (int j = 0; j < 2; j++) {
      int c = tid + j * 512;
      int row = c >> 3, cc = c & 7;
      int dst = row * 128 + ((cc * 16) ^ ((row & 7) << 4));
      {
        const float* src = P + (size_t)(m0 + row) * 256 + k0 + cc * 8;
        f32x4 x = *(const f32x4*)src;
        f32x4 y = *(const f32x4*)(src + 4);
        s16x8 pk;
        pk[0] = (short)f2bf(x[0]); pk[1] = (short)f2bf(x[1]);
        pk[2] = (short)f2bf(x[2]); pk[3] = (short)f2bf(x[3]);
        pk[4] = (short)f2bf(y[0]); pk[5] = (short)f2bf(y[1]);
        pk[6] = (short)f2bf(y[2]); pk[7] = (short)f2bf(y[3]);
        *(s16x8*)(Pl + dst) = pk;
      }
      {
        const float* src = Q + (size_t)(n0 + row) * 256 + k0 + cc * 8;
        f32x4 x = *(const f32x4*)src;
        f32x4 y = *(const f32x4*)(src + 4);
        s16x8 pk;
        pk[0] = (short)f2bf(x[0]); pk[1] = (short)f2bf(x[1]);
        pk[2] = (short)f2bf(x[2]); pk[3] = (short)f2bf(x[3]);
        pk[4] = (short)f2bf(y[0]); pk[5] = (short)f2bf(y[1]);
        pk[6] = (short)f2bf(y[2]); pk[7] = (short)f2bf(y[3]);
        *(s16x8*)(Ql + dst) = pk;
      }
    }
    __syncthreads();
#pragma unroll
    for (int ks = 0; ks < 2; ks++) {
      s16x8 af[4], bf[2];
      int kbyte = ks * 64 + lg * 16;
#pragma unroll
      for (int fm = 0; fm < 4; fm++) {
        int row = wm * 64 + fm * 16 + lr;
        af[fm] = *(const s16x8*)(Pl + row * 128 + (kbyte ^ ((row & 7) << 4)));
      }
#pragma unroll
      for (int fn = 0; fn < 2; fn++) {
        int row = wn * 32 + fn * 16 + lr;
        bf[fn] = *(const s16x8*)(Ql + row * 128 + (kbyte ^ ((row & 7) << 4)));
      }
#pragma unroll
      for (int fm = 0; fm < 4; fm++)
#pragma unroll
        for (int fn = 0; fn < 2; fn++)
          acc[fm][fn] = __builtin_amdgcn_mfma_f32_16x16x32_bf16(
              af[fm], bf[fn], acc[fm][fn], 0, 0, 0);
    }
  }

  if (MODE == 0) {
    float bv[2];
#pragma unroll
    for (int fn = 0; fn < 2; fn++) bv[fn] = bias[n0 + wn * 32 + fn * 16 + lr];
#pragma unroll
    for (int fm = 0; fm < 4; fm++)
#pragma unroll
      for (int i = 0; i < 4; i++) {
        int m = m0 + wm * 64 + fm * 16 + lg * 4 + i;
#pragma unroll
        for (int fn = 0; fn < 2; fn++) {
          int n = n0 + wn * 32 + fn * 16 + lr;
          out[(size_t)m * 256 + n] = f2bf(acc[fm][fn][i] + bv[fn]);
        }
      }
  } else {
#pragma unroll
    for (int fm = 0; fm < 4; fm++)
#pragma unroll
      for (int i = 0; i < 4; i++) {
        int m = m0 + wm * 64 + fm * 16 + lg * 4 + i;  // d index
        float bm = bias[m];
#pragma unroll
        for (int fn = 0; fn < 2; fn++) {
          int n = n0 + wn * 32 + fn * 16 + lr;  // global key row
          int bb = n >> 11, nn = n & 2047;
          out[(size_t)bb * 524288 + (size_t)m * 2048 + nn] =
              f2bf(acc[fm][fn][i] + bm);
        }
      }
  }
}

// ---------------------------------------------------------------------------
// Attention. grid 512 = B(32) x q-tiles(16), 512 thr / 8 waves, 64 q-rows.
// Per 64-key tile, 5 phases: stage K/vT -> QK^T MFMA -> sacc->Sf(LDS,f32) ->
// cooperative vectorized epilogue (bias f32x4 load [prefetched], exp, mask,
// weights f32x4 store, bf16->Sl, scalar rowsum) -> PV MFMA.
// All global accesses PLAIN (round-3 lesson: NT hints bypassed L3, 7x fetch).
// LDS 64KB: Kl[0,32K)+Vl[32K,64K); Sf[0,16K)+Sl[16K,24K) alias dead Kl.
// ---------------------------------------------------------------------------
__global__ __launch_bounds__(512, 2) void attn_kernel(
    const unsigned short* __restrict__ qb, const unsigned short* __restrict__ kb,
    const unsigned short* __restrict__ vT, const int* __restrict__ qmask,
    const int* __restrict__ kmask, const float* __restrict__ bias,
    float* __restrict__ out, float* __restrict__ weights,
    float* __restrict__ rowrecip_ws) {
  __shared__ __align__(16) char lds[65536];
  char* Kl = lds;            // [64][512B] swizzled bf16 K-tile
  char* Vl = lds + 32768;    // [256][128B] swizzled bf16 vT-tile
  char* Sf = lds;            // [64][256B] f32 scores, bank-rotated (alias Kl)
  char* Sl = lds + 16384;    // [64][128B] bf16 scores, swizzled (alias Kl)
  float* rowsum_lds = (float*)lds;  // [64] reciprocals, after k-loop only

  int bid = blockIdx.x;
  int swz = (bid & 7) * 64 + (bid >> 3);  // XCD swizzle (512 % 8 == 0)
  int b = swz >> 4, qt = swz & 15;
  int q0 = qt * 64;
  const int tid = threadIdx.x, lane = tid & 63, w = tid >> 6;
  const int lr = lane & 15, lg = lane >> 4;
  const int wm = w >> 2, wn = w & 3;

  // phase-B (epilogue) mapping: row pr = tid/8, chunks pc and pc+8 (4 cols ea)
  const int pr = tid >> 3, pc = tid & 7;
  const int qrow_pb = b * 1024 + q0 + pr;
  const int qm_pb = qmask[qrow_pb];
  const float* bias_row = bias + (size_t)qrow_pb * 2048;
  float* wrow = weights + (size_t)qrow_pb * 2048;
  const int* kmask_b = kmask + b * 2048;
  const int prot = ((pr >> 2) & 3) * 64;  // Sf bank rotation for this row

  // Hoisted Q fragments (64 VGPRs)
  s16x8 qf[2][8];
  {
    const unsigned short* qbase =
        qb + (size_t)(b * 1024 + q0 + wm * 32 + lr) * 256 + lg * 8;
#pragma unroll
    for (int fm = 0; fm < 2; fm++)
#pragma unroll
      for (int ks = 0; ks < 8; ks++)
        qf[fm][ks] = *(const s16x8*)(qbase + fm * 16 * 256 + ks * 32);
  }

  f32x4 acc_o[2][4];
#pragma unroll
  for (int a = 0; a < 2; a++)
#pragma unroll
    for (int c = 0; c < 4; c++) acc_o[a][c] = (f32x4){0.f, 0.f, 0.f, 0.f};
  float rs = 0.f;

  const size_t kb_base = (size_t)b * 2048 * 256;
  const size_t vT_base = (size_t)b * 256 * 2048;

  // bias prefetch (tile 0)
  f32x4 bcur0 = *(const f32x4*)(bias_row + pc * 4);
  f32x4 bcur1 = *(const f32x4*)(bias_row + (pc + 8) * 4);

  for (int kt = 0; kt < 32; kt++) {
    __syncthreads();  // PV + epilogue of kt-1 fully done
    // ---- stage K tile and vT tile (swizzled) ----
#pragma unroll
    for (int j = 0; j < 4; j++) {
      int c = tid + j * 512;
      {
        int row = c >> 5, cb = (c & 31) * 16;
        s16x8 kv = *(const s16x8*)(kb + kb_base +
                                   (size_t)(kt * 64 + row) * 256 + (cb >> 1));
        *(s16x8*)(Kl + row * 512 + (cb ^ ((row & 7) << 4))) = kv;
      }
      {
        int row = c >> 3, cb = (c & 7) * 16;
        s16x8 vv = *(const s16x8*)(vT + vT_base + (size_t)row * 2048 +
                                   kt * 64 + (cb >> 1));
        *(s16x8*)(Vl + row * 128 + (cb ^ ((row & 7) << 4))) = vv;
      }
    }
    __syncthreads();
    // ---- QK^T: wave's 16 key-cols ----
    f32x4 sacc[2];
    sacc[0] = (f32x4){0.f, 0.f, 0.f, 0.f};
    sacc[1] = (f32x4){0.f, 0.f, 0.f, 0.f};
    {
      int krow = wn * 16 + lr;
      int swzk = (krow & 7) << 4;
#pragma unroll
      for (int ks = 0; ks < 8; ks++) {
        s16x8 bfr = *(const s16x8*)(Kl + krow * 512 + ((ks * 64 + lg * 16) ^ swzk));
        sacc[0] = __builtin_amdgcn_mfma_f32_16x16x32_bf16(qf[0][ks], bfr, sacc[0], 0, 0, 0);
        sacc[1] = __builtin_amdgcn_mfma_f32_16x16x32_bf16(qf[1][ks], bfr, sacc[1], 0, 0, 0);
      }
    }
    __syncthreads();  // Kl dead -> Sf/Sl may be written
    // ---- sacc -> Sf (f32, bank-rotated rows) ----
    {
      int col4 = (wn * 16 + lr) * 4;
#pragma unroll
      for (int fm = 0; fm < 2; fm++)
#pragma unroll
        for (int i = 0; i < 4; i++) {
          int row = wm * 32 + fm * 16 + lg * 4 + i;
          *(float*)(Sf + row * 256 + ((col4 + ((row >> 2) & 3) * 64) & 255)) =
              sacc[fm][i];
        }
    }
    __syncthreads();
    // ---- phase B: vectorized epilogue ----
    {
      int ktn = (kt + 1) & 31;  // prefetch next tile's bias (kt=31: unused)
      f32x4 bn0 = *(const f32x4*)(bias_row + ktn * 64 + pc * 4);
      f32x4 bn1 = *(const f32x4*)(bias_row + ktn * 64 + (pc + 8) * 4);
#pragma unroll
      for (int half = 0; half < 2; half++) {
        int c = pc + half * 8;
        f32x4 bv = half ? bcur1 : bcur0;
        f32x4 sv = *(const f32x4*)(Sf + pr * 256 + ((c * 16 + prot) & 255));
        i32x4 kmv = *(const i32x4*)(kmask_b + kt * 64 + c * 4);
        f32x4 sval;
#pragma unroll
        for (int j = 0; j < 4; j++) {
          float lgt = sv[j] * 0.0625f + bv[j];
          float e = kmv[j] ? __expf(lgt) : 0.0f;
          sval[j] = qm_pb ? e : 1.0f;
        }
        rs += sval[0] + sval[1] + sval[2] + sval[3];
        *(f32x4*)(wrow + kt * 64 + c * 4) = sval;
        s16x4 h;
        h[0] = (short)f2bf(sval[0]);
        h[1] = (short)f2bf(sval[1]);
        h[2] = (short)f2bf(sval[2]);
        h[3] = (short)f2bf(sval[3]);
        int cb = c * 8;
        int sb = pr * 128 + ((cb & ~15) ^ ((pr & 7) << 4)) + (cb & 15);
        *(s16x4*)(Sl + sb) = h;
      }
      bcur0 = bn0;
      bcur1 = bn1;
    }
    __syncthreads();  // Sl complete before PV reads it
    // ---- PV: O += S * V ----
#pragma unroll
    for (int ks = 0; ks < 2; ks++) {
      int kbyte = ks * 64 + lg * 16;
      s16x8 af[2], bfr[4];
#pragma unroll
      for (int fm = 0; fm < 2; fm++) {
        int row = wm * 32 + fm * 16 + lr;
        af[fm] = *(const s16x8*)(Sl + row * 128 + (kbyte ^ ((row & 7) << 4)));
      }
#pragma unroll
      for (int fn = 0; fn < 4; fn++) {
        int row = wn * 64 + fn * 16 + lr;
        bfr[fn] = *(const s16x8*)(Vl + row * 128 + (kbyte ^ ((row & 7) << 4)));
      }
#pragma unroll
      for (int fm = 0; fm < 2; fm++)
#pragma unroll
        for (int fn = 0; fn < 4; fn++)
          acc_o[fm][fn] = __builtin_amdgcn_mfma_f32_16x16x32_bf16(
              af[fm], bfr[fn], acc_o[fm][fn], 0, 0, 0);
    }
  }
  // ---- rowsum: 8-lane group reduce, store reciprocal ----
  {
    float tot = rs;
    tot += __shfl_xor(tot, 1);
    tot += __shfl_xor(tot, 2);
    tot += __shfl_xor(tot, 4);
    float rinv = 1.0f / tot;
    if ((tid & 7) == 0) {
      rowsum_lds[pr] = rinv;                       // disjoint from Sl/Vl reads
      rowrecip_ws[b * 1024 + q0 + pr] = rinv;
    }
  }
  __syncthreads();
  // ---- normalized O store ----
#pragma unroll
  for (int fm = 0; fm < 2; fm++)
#pragma unroll
    for (int i = 0; i < 4; i++) {
      int srow = wm * 32 + fm * 16 + lg * 4 + i;
      float rinv = rowsum_lds[srow];
      int qrow = q0 + srow;
#pragma unroll
      for (int fn = 0; fn < 4; fn++) {
        int d = wn * 64 + fn * 16 + lr;
        out[((size_t)b * 1024 + qrow) * 256 + d] = acc_o[fm][fn][i] * rinv;
      }
    }
}

// ---------------------------------------------------------------------------
// Rescale: weights[b,q,:] *= rinv[b,q]  (reciprocal precomputed; plain ops)
// ---------------------------------------------------------------------------
__global__ __launch_bounds__(256) void rescale_kernel(
    float* __restrict__ weights, const float* __restrict__ rinvarr) {
  const size_t total = (size_t)32 * 1024 * 2048 / 4;  // float4 count
  size_t stride = (size_t)gridDim.x * blockDim.x;
  for (size_t i = (size_t)blockIdx.x * blockDim.x + threadIdx.x; i < total;
       i += stride) {
    size_t row = i >> 9;  // 512 float4 per 2048-row
    float rinv = rinvarr[row];
    f32x4 v = ((const f32x4*)weights)[i];
    v[0] *= rinv; v[1] *= rinv; v[2] *= rinv; v[3] *= rinv;
    ((f32x4*)weights)[i] = v;
  }
}

extern "C" void kernel_launch(void* const* d_in, const int* in_sizes, int n_in,
                              void* d_out, int out_size, void* d_ws,
                              size_t ws_size, hipStream_t stream) {
  const float* query = (const float*)d_in[0];
  const float* key = (const float*)d_in[1];
  const float* value = (const float*)d_in[2];
  const int* qmask = (const int*)d_in[3];
  const int* kmask = (const int*)d_in[4];
  const float* bias = (const float*)d_in[5];
  const float* Wq = (const float*)d_in[6];
  const float* bq = (const float*)d_in[7];
  const float* Wk = (const float*)d_in[8];
  const float* bk = (const float*)d_in[9];
  const float* Wv = (const float*)d_in[10];
  const float* bv = (const float*)d_in[11];

  float* out = (float*)d_out;
  float* weights = out + (size_t)32 * 1024 * 256;

  char* ws = (char*)d_ws;
  unsigned short* qb = (unsigned short*)ws;                // 16 MB
  unsigned short* kbb = (unsigned short*)(ws + 16777216);  // 32 MB
  unsigned short* vT = (unsigned short*)(ws + 50331648);   // 32 MB
  float* rowrecip = (float*)(ws + 83886080);               // 128 KB

  proj_kernel<0><<<dim3(256, 2), 512, 0, stream>>>(query, Wq, bq, qb);
  proj_kernel<0><<<dim3(512, 2), 512, 0, stream>>>(key, Wk, bk, kbb);
  proj_kernel<1><<<dim3(2, 512), 512, 0, stream>>>(Wv, value, bv, vT);
  attn_kernel<<<dim3(512), 512, 0, stream>>>(qb, kbb, vT, qmask, kmask, bias,
                                             out, weights, rowrecip);
  rescale_kernel<<<dim3(2048), 256, 0, stream>>>(weights, rowrecip);
}